// Round 1
// baseline (186.075 us; speedup 1.0000x reference)
//
#include <hip/hip_runtime.h>
#include <hip/hip_bf16.h>

// ExpansionContrastModule on MI355X.
// b=2, C=32, H=W=256, kv grid 64x64, shifts (1,2,4), 8 diff kernels.
// THIS ROUND: only K1 changed — restructured from wave=(2co x 16ci), grid 1024
// (16x input re-read, ~671 MB L2 traffic) to wave=(16co x 4ci), grid 256
// (2x re-read, ~82 MB), 8 waves/block with LDS partial combine, plus bijective
// XCD-chunk swizzle so each XCD's cen working set (~2.2 MB) fits its 4 MB L2.
// K2i/K2f/K3a/K3b byte-identical to previous passing round.
// Pipeline: k1 -> k2i -> k2f -> k3a -> k3b. pars aliases v tail (consumed before k3a).

#define CC 32
#define HW 256
#define KVW 64

// ---------------- K1: 5x5 stride-4 pad-2 conv + bias -> kv [2,32,64,64] ----------------
// grid 256 = b(2) x y(64) x coh(2), 512 threads = 8 waves.
// Wave w handles ci range [4w, 4w+4), computes partials for all 16 co of this co-half,
// writes part[w][co][x] to LDS; after barrier, 1024 outputs combined by 512 threads.
__global__ __launch_bounds__(512, 2) void k1_trans(const float* __restrict__ cen,
                                                   const float* __restrict__ tW,
                                                   const float* __restrict__ tB,
                                                   float* __restrict__ kv) {
  __shared__ alignas(16) float part[8][16][64];  // [ci-group][co][x], 32 KB
  // Bijective XCD-chunk swizzle: 256 blocks, 8 XCDs, 32 blocks/XCD contiguous.
  int bid0 = blockIdx.x;
  int bid = (bid0 & 7) * 32 + (bid0 >> 3);
  int b = bid >> 7, y = (bid >> 1) & 63, coh = bid & 1;
  int tid = threadIdx.x;
  int x = tid & 63;
  int w = __builtin_amdgcn_readfirstlane(tid >> 6);  // wave id 0..7 = ci-group
  int ci0 = w * 4;
  int co0 = coh * 16;

  float acc[16];
#pragma unroll
  for (int co = 0; co < 16; co++) acc[co] = 0.f;

  // Output row y taps input rows 4y-2+r, r=0..4. Max row 254 (in bounds);
  // only y==0 has rows -2,-1 -> clamp offset, zero the loaded rows (branch-free FMAs).
  int roff[5];
  bool rok[5];
#pragma unroll
  for (int r = 0; r < 5; r++) {
    int row = 4 * y - 2 + r;
    rok[r] = (row >= 0);
    roff[r] = (row < 0 ? 0 : row) * HW;
  }

  const float4 z4 = {0.f, 0.f, 0.f, 0.f};

#pragma unroll
  for (int cc = 0; cc < 4; cc++) {
    int ci = ci0 + cc;
    const float* pc = cen + (size_t)(b * CC + ci) * 65536 + 4 * x;
    float4 A[5], B[5];
#pragma unroll
    for (int r = 0; r < 5; r++) {
      A[r] = (rok[r] && x > 0) ? *(const float4*)(pc + roff[r] - 4) : z4;  // 4x-4..4x-1
      B[r] = rok[r] ? *(const float4*)(pc + roff[r]) : z4;                 // 4x..4x+3
    }
#pragma unroll
    for (int co = 0; co < 16; co++) {
      const float* wp = tW + ((co0 + co) * CC + ci) * 25;  // uniform -> s_load
#pragma unroll
      for (int r = 0; r < 5; r++) {
        acc[co] += wp[r * 5 + 0] * A[r].z + wp[r * 5 + 1] * A[r].w +
                   wp[r * 5 + 2] * B[r].x + wp[r * 5 + 3] * B[r].y +
                   wp[r * 5 + 4] * B[r].z;
      }
    }
  }

#pragma unroll
  for (int co = 0; co < 16; co++) part[w][co][x] = acc[co];
  __syncthreads();

  // Combine 8 ci-group partials: 1024 outputs (16 co x 64 x), 512 threads -> 2 each.
#pragma unroll
  for (int k = 0; k < 2; k++) {
    int o = tid + k * 512;
    int co = o >> 6, xx = o & 63;
    float s = 0.f;
#pragma unroll
    for (int ww = 0; ww < 8; ww++) s += part[ww][co][xx];
    kv[((b * CC + co0 + co) * KVW + y) * KVW + xx] = s + tB[co0 + co];
  }
}

// ---------------- K2i: per-(b,c,i) partials D[8], M[8], Q2 (verbatim) --------
__device__ inline float wred64(float v) {
#pragma unroll
  for (int off = 1; off < 64; off <<= 1) v += __shfl_xor(v, off);
  return v;
}

__global__ __launch_bounds__(1024) void k2i_partial(const float* __restrict__ kv,
                                                    const float* __restrict__ qW,
                                                    const float* __restrict__ kW,
                                                    float* __restrict__ pars) {
  __shared__ alignas(16) float kl[4096];  // full 64x64 k_i map (16 KB), no halo
  __shared__ float wredl[16][18];         // per-wave: D[8], M[8], Q2[16]
  int bid = blockIdx.x;  // 192 = bc(64) * 3 + i
  int bc = bid / 3, i = bid - bc * 3;
  int b = bc >> 5, c = bc & 31;
  int tid = threadIdx.x;
  int lane = tid & 63, w = tid >> 6;  // w 0..15
  int xx = tid & 63;
  int ybase = tid >> 6;  // thread's rows are r*16 + ybase

  float qreg[4];
#pragma unroll
  for (int r = 0; r < 4; r++) {
    int px = r * 1024 + tid;  // row = r*16 + ybase, col = xx
    float q = 0.f, kk = 0.f;
    for (int ci = 0; ci < CC; ci++) {
      float val = kv[(b * CC + ci) * 4096 + px];
      q += qW[c * CC + ci] * val;
      kk += kW[(i * CC + c) * CC + ci] * val;
    }
    qreg[r] = q;
    kl[px] = kk;
  }
  __syncthreads();

  float q2 = 0.f;
#pragma unroll
  for (int r = 0; r < 4; r++) q2 += qreg[r] * qreg[r];
  q2 = wred64(q2);
  if (lane == 0) wredl[w][16] = q2;

  constexpr int DYt[8] = {-1, -1, -1, 0, 1, 1, 1, 0};
  constexpr int DXt[8] = {-1, 0, 1, 1, 1, 0, -1, -1};
  const int d = 1 << i;
#pragma unroll
  for (int n = 0; n < 8; n++) {
    const int dy = DYt[n], dx = DXt[n];
    int xn = xx + dx * d;
    bool xok = (xn >= 0 && xn < KVW);
    float dacc = 0.f, macc = 0.f;
#pragma unroll
    for (int r = 0; r < 4; r++) {
      int yy = r * 16 + ybase;
      int px = yy * KVW + xx;
      float kc = kl[px];
      int yn = yy + dy * d;
      float kn = (xok && yn >= 0 && yn < KVW) ? kl[yn * KVW + xn] : 0.f;
      float df = kc - kn;
      dacc += qreg[r] * df;
      macc += df * df;
    }
    dacc = wred64(dacc);
    macc = wred64(macc);
    if (lane == 0) {
      wredl[w][n] = dacc;
      wredl[w][8 + n] = macc;
    }
  }
  __syncthreads();

  float* pp = pars + (size_t)bid * 32;
  if (tid < 8) {
    float D = 0.f, M = 0.f;
    for (int w2 = 0; w2 < 16; w2++) {
      D += wredl[w2][tid];
      M += wredl[w2][8 + tid];
    }
    pp[tid] = D;
    pp[8 + tid] = M;
  }
  if (tid == 0) {
    float Q = 0.f;
    for (int w2 = 0; w2 < 16; w2++) Q += wredl[w2][16];
    pp[16] = Q;
  }
}

// ---------------- K2f: finalize scores [2,32,24] (verbatim) ----------
__global__ __launch_bounds__(64) void k2f_finalize(const float* __restrict__ pars,
                                                   float* __restrict__ scores) {
  __shared__ float srl[24];
  int bc = blockIdx.x;  // 64 = b*32 + c
  int t = threadIdx.x;
  if (t < 24) {
    int i = t >> 3, n = t & 7;
    const float* pp = pars + (size_t)(bc * 3 + i) * 32;
    float D = pp[n];
    float M = pp[8 + n];
    float Q = pars[(size_t)(bc * 3) * 32 + 16];  // Q2 identical across i; use i=0's
    float sr = D / (fmaxf(sqrtf(M), 1e-12f) * fmaxf(sqrtf(Q), 1e-12f));
    srl[t] = sr;
  }
  __syncthreads();
  if (t < 24) {
    float r2 = 0.f;
    for (int j = 0; j < 24; j++) r2 += srl[j] * srl[j];
    scores[bc * 24 + t] = srl[t] / fmaxf(sqrtf(r2), 1e-12f);
  }
}

// ---------------- K3a: v[i][b][c][px], bf16, 2 px/thread (verbatim) ----------
__global__ __launch_bounds__(256) void k3a_values(const float* __restrict__ cen,
                                                  const float* __restrict__ vW,
                                                  __hip_bfloat16* __restrict__ v) {
  int bid = blockIdx.x;  // 1024 = b(2) x blk(512)
  int b = bid >> 9, blk = bid & 511;
  int tid = threadIdx.x;
  int lane = tid & 63;
  int cg = __builtin_amdgcn_readfirstlane(tid >> 6);  // wave-uniform c group (8 c)
  int px = blk * 128 + lane * 2;

  float2 cr[CC];
#pragma unroll
  for (int ci = 0; ci < CC; ci++)
    cr[ci] = *(const float2*)(cen + (size_t)(b * CC + ci) * 65536 + px);

#pragma unroll
  for (int i = 0; i < 3; i++) {
#pragma unroll
    for (int cc = 0; cc < 8; cc++) {
      int c = cg * 8 + cc;
      const float* wp = vW + (i * CC + c) * CC;  // uniform -> s_load
      float a0 = 0.f, a1 = 0.f;
#pragma unroll
      for (int ci = 0; ci < CC; ci++) {
        a0 += wp[ci] * cr[ci].x;
        a1 += wp[ci] * cr[ci].y;
      }
      __hip_bfloat16 h0 = __float2bfloat16(a0);
      __hip_bfloat16 h1 = __float2bfloat16(a1);
      unsigned int pk = (unsigned int)(*(unsigned short*)&h0) |
                        ((unsigned int)(*(unsigned short*)&h1) << 16);
      *(unsigned int*)((unsigned short*)v + (((size_t)((i * 2 + b) * CC + c)) << 16) +
                       px) = pk;
    }
  }
}

// ---------------- K3b: combine taps + out conv + BN + ReLU (verbatim) --------
__global__ __launch_bounds__(256) void k3b_combine(const __hip_bfloat16* __restrict__ v,
                                                   const float* __restrict__ scores,
                                                   const float* __restrict__ oW,
                                                   const float* __restrict__ gamma,
                                                   const float* __restrict__ beta,
                                                   const float* __restrict__ mean,
                                                   const float* __restrict__ var,
                                                   float* __restrict__ out) {
  __shared__ alignas(16) float vt[3 * 24 * 24 * 4];  // [i][r][col][cp] halo-4 tiles
  __shared__ alignas(16) float sl[27][32];           // 0..23: s[j][c]; 24..26: S_i[c]
  __shared__ alignas(16) float owl[32][32];          // [co][c]
  __shared__ float bns[32], bnb[32];

  int bid = blockIdx.x;
  int b = bid >> 8, tile = bid & 255;
  int ty = tile >> 4, tx = tile & 15;
  int tid = threadIdx.x;
  int ly = tid >> 4, lx = tid & 15;

  for (int f = tid; f < 24 * 32; f += 256) {
    int j = f >> 5, c = f & 31;
    sl[j][c] = scores[(b * CC + c) * 24 + j];
  }
  for (int f = tid; f < 1024; f += 256) owl[f >> 5][f & 31] = oW[f];
  if (tid < 32) {
    float inv = rsqrtf(var[tid] + 1e-5f);
    float sc = gamma[tid] * inv;
    bns[tid] = sc;
    bnb[tid] = beta[tid] - mean[tid] * sc;
  }
  __syncthreads();
  if (tid < 32) {
#pragma unroll
    for (int i = 0; i < 3; i++) {
      float s = 0.f;
      for (int n = 0; n < 8; n++) s += sl[i * 8 + n][tid];
      sl[24 + i][tid] = s;
    }
  }

  int ldsoff[4], pxoff[4], ibase[4];
  bool okp[4];
#pragma unroll
  for (int it = 0; it < 4; it++) {
    int p = tid + it * 256;
    bool act = (p < 864);
    int pp = act ? p : 0;
    int i = pp / 288;
    int rem = pp - i * 288;
    int r = rem / 12;
    int col = (rem - r * 12) * 2;
    int gy = ty * 16 + r - 4, gx = tx * 16 + col - 4;
    okp[it] = act && gy >= 0 && gy < HW && gx >= 0 && gx < HW;
    pxoff[it] = gy * HW + gx;
    ibase[it] = (i * 2 + b) * CC;
    ldsoff[it] = ((i * 24 + r) * 24 + col) * 4;
  }

  constexpr int DYt[8] = {-1, -1, -1, 0, 1, 1, 1, 0};
  constexpr int DXt[8] = {-1, 0, 1, 1, 1, 0, -1, -1};

  float acc[32];
#pragma unroll
  for (int co = 0; co < 32; co++) acc[co] = 0.f;

  unsigned int pf[4][4];
  const unsigned short* vs = (const unsigned short*)v;

#pragma unroll
  for (int it = 0; it < 4; it++)
#pragma unroll
    for (int cp = 0; cp < 4; cp++)
      pf[it][cp] = okp[it]
                       ? *(const unsigned int*)(vs + (((size_t)(ibase[it] + cp)) << 16) +
                                                pxoff[it])
                       : 0u;

  for (int cg = 0; cg < 8; cg++) {
    __syncthreads();
#pragma unroll
    for (int it = 0; it < 4; it++) {
      if (it == 3 && tid >= 96) continue;  // p >= 864
      float4 lo, hi;
      lo.x = __uint_as_float(pf[it][0] << 16);
      lo.y = __uint_as_float(pf[it][1] << 16);
      lo.z = __uint_as_float(pf[it][2] << 16);
      lo.w = __uint_as_float(pf[it][3] << 16);
      hi.x = __uint_as_float(pf[it][0] & 0xffff0000u);
      hi.y = __uint_as_float(pf[it][1] & 0xffff0000u);
      hi.z = __uint_as_float(pf[it][2] & 0xffff0000u);
      hi.w = __uint_as_float(pf[it][3] & 0xffff0000u);
      *(float4*)&vt[ldsoff[it]] = lo;
      *(float4*)&vt[ldsoff[it] + 4] = hi;
    }
    if (cg < 7) {
      int cb = (cg + 1) * 4;
#pragma unroll
      for (int it = 0; it < 4; it++)
#pragma unroll
        for (int cp = 0; cp < 4; cp++)
          pf[it][cp] = okp[it] ? *(const unsigned int*)(vs +
                                                        (((size_t)(ibase[it] + cb + cp))
                                                         << 16) +
                                                        pxoff[it])
                               : 0u;
    }
    __syncthreads();

    float4 pre = {0.f, 0.f, 0.f, 0.f};
#pragma unroll
    for (int i = 0; i < 3; i++) {
      const int d = 1 << i;
      float4 S4 = *(const float4*)&sl[24 + i][cg * 4];
      float4 ctr = *(const float4*)&vt[((i * 24 + (ly + 4)) * 24 + (lx + 4)) * 4];
      pre.x += S4.x * ctr.x;
      pre.y += S4.y * ctr.y;
      pre.z += S4.z * ctr.z;
      pre.w += S4.w * ctr.w;
#pragma unroll
      for (int n = 0; n < 8; n++) {
        float4 sj = *(const float4*)&sl[i * 8 + n][cg * 4];
        float4 nb = *(const float4*)&vt[((i * 24 + (ly + 4 + DYt[n] * d)) * 24 +
                                         (lx + 4 + DXt[n] * d)) * 4];
        pre.x -= sj.x * nb.x;
        pre.y -= sj.y * nb.y;
        pre.z -= sj.z * nb.z;
        pre.w -= sj.w * nb.w;
      }
    }
#pragma unroll
    for (int co = 0; co < 32; co++) {
      float4 ow = *(const float4*)&owl[co][cg * 4];
      acc[co] += ow.x * pre.x + ow.y * pre.y + ow.z * pre.z + ow.w * pre.w;
    }
  }

  int gy = ty * 16 + ly, gx = tx * 16 + lx;
#pragma unroll
  for (int co = 0; co < 32; co++) {
    float val = acc[co] * bns[co] + bnb[co];
    out[((size_t)(b * CC + co) << 16) + gy * HW + gx] = fmaxf(val, 0.f);
  }
}

extern "C" void kernel_launch(void* const* d_in, const int* in_sizes, int n_in,
                              void* d_out, int out_size, void* d_ws, size_t ws_size,
                              hipStream_t stream) {
  const float* cen = (const float*)d_in[0];
  const float* trans_W = (const float*)d_in[1];
  const float* trans_b = (const float*)d_in[2];
  const float* query_W = (const float*)d_in[3];
  const float* value_W = (const float*)d_in[4];
  const float* key_W = (const float*)d_in[5];
  const float* out_W = (const float*)d_in[6];
  const float* bn_gamma = (const float*)d_in[7];
  const float* bn_beta = (const float*)d_in[8];
  const float* bn_mean = (const float*)d_in[9];
  const float* bn_var = (const float*)d_in[10];
  float* out = (float*)d_out;

  // workspace layout — unchanged:
  //   kv     [0,        524288)
  //   scores [524288,   530432)
  //   v      [532480,   25698304)  (bf16)
  //   pars   [25673728, 25698304)  -- aliases v tail; consumed by k2f before k3a.
  float* kv = (float*)d_ws;
  float* scores = (float*)((char*)d_ws + 524288);
  __hip_bfloat16* v = (__hip_bfloat16*)((char*)d_ws + 532480);
  float* pars = (float*)((char*)d_ws + 25673728);

  k1_trans<<<256, 512, 0, stream>>>(cen, trans_W, trans_b, kv);
  k2i_partial<<<192, 1024, 0, stream>>>(kv, query_W, key_W, pars);
  k2f_finalize<<<64, 64, 0, stream>>>(pars, scores);
  k3a_values<<<1024, 256, 0, stream>>>(cen, value_W, v);  // clobbers pars (ok)
  k3b_combine<<<512, 256, 0, stream>>>(v, scores, out_W, bn_gamma, bn_beta, bn_mean,
                                       bn_var, out);
}

// Round 2
// 169.652 us; speedup vs baseline: 1.0968x; 1.0968x over previous
//
#include <hip/hip_runtime.h>
#include <hip/hip_bf16.h>

// ExpansionContrastModule on MI355X.
// b=2, C=32, H=W=256, kv grid 64x64, shifts (1,2,4), 8 diff kernels.
// THIS ROUND: revert K1 to the proven round-0 shape (grid 1024 = b x cog(8) x y,
// 256 threads / 4 waves, same occupancy + weight s_load pattern) with ONE change:
// wave split is now (ci-quarter x all-4-co) instead of (co-pair x ci-half).
// Each wave loads 8 ci (80 float4/thread, was 160) -> VMEM issue halves
// (~671 MB -> ~336 MB cache-side); FMA count and weight traffic unchanged.
// K2i/K2f/K3a/K3b byte-identical to round-0 passing.
// Pipeline: k1 -> k2i -> k2f -> k3a -> k3b. pars aliases v tail (consumed before k3a).

#define CC 32
#define HW 256
#define KVW 64

// ---------------- K1: 5x5 stride-4 pad-2 conv + bias -> kv [2,32,64,64] ----------------
// grid 1024 = b(2) x cog(8) x y(64); 4 waves: wave w -> ci range [8w, 8w+8),
// computes all 4 co of this cog. Partials combined via LDS (4 KB).
__global__ __launch_bounds__(256, 2) void k1_trans(const float* __restrict__ cen,
                                                   const float* __restrict__ tW,
                                                   const float* __restrict__ tB,
                                                   float* __restrict__ kv) {
  __shared__ alignas(16) float part[4][4][64];  // [ci-quarter][co][x], 4 KB
  int bid = blockIdx.x;
  int b = bid >> 9, cog = (bid >> 6) & 7, y = bid & 63;
  int tid = threadIdx.x;
  int x = tid & 63;
  int w = __builtin_amdgcn_readfirstlane(tid >> 6);  // wave id 0..3 = ci quarter
  int ci0 = w * 8;                                   // this wave's ci range [ci0, ci0+8)
  int co0 = cog * 4;                                 // block's 4 output channels

  float acc[4] = {0.f, 0.f, 0.f, 0.f};
  const float4 z4 = {0.f, 0.f, 0.f, 0.f};

  // Output row y taps input rows 4y-2+r, r=0..4. Max row 254 (in bounds);
  // only y==0 has rows -2,-1 -> clamp+skip (block-uniform).
  int roff[5];
  bool rok[5];
#pragma unroll
  for (int r = 0; r < 5; r++) {
    int row = 4 * y - 2 + r;
    rok[r] = (row >= 0);
    roff[r] = (row < 0 ? 0 : row) * HW;
  }

  for (int cc4 = 0; cc4 < 8; cc4 += 4) {
    int ci = ci0 + cc4;
    const float* pc[4];
#pragma unroll
    for (int c = 0; c < 4; c++) pc[c] = cen + (size_t)(b * CC + ci + c) * 65536 + 4 * x;
    float4 A[4][5], B[4][5];
#pragma unroll
    for (int c = 0; c < 4; c++) {
#pragma unroll
      for (int r = 0; r < 5; r++) {
        A[c][r] = (x > 0) ? *(const float4*)(pc[c] + roff[r] - 4) : z4;  // 4x-4..4x-1
        B[c][r] = *(const float4*)(pc[c] + roff[r]);                     // 4x..4x+3
      }
    }
#pragma unroll
    for (int r = 0; r < 5; r++) {
      if (!rok[r]) continue;  // block-uniform (only y==0, r<2)
#pragma unroll
      for (int c = 0; c < 4; c++) {
#pragma unroll
        for (int co = 0; co < 4; co++) {
          const float* wa = tW + ((co0 + co) * CC + ci + c) * 25 + r * 5;  // s_load
          acc[co] += wa[0] * A[c][r].z + wa[1] * A[c][r].w + wa[2] * B[c][r].x +
                     wa[3] * B[c][r].y + wa[4] * B[c][r].z;
        }
      }
    }
  }

#pragma unroll
  for (int co = 0; co < 4; co++) part[w][co][x] = acc[co];
  __syncthreads();

  // 256 outputs (4 co x 64 x), 256 threads -> 1 each.
  {
    int co = tid >> 6, xx = tid & 63;
    float s = part[0][co][xx] + part[1][co][xx] + part[2][co][xx] + part[3][co][xx];
    kv[((b * CC + co0 + co) * KVW + y) * KVW + xx] = s + tB[co0 + co];
  }
}

// ---------------- K2i: per-(b,c,i) partials D[8], M[8], Q2 (verbatim) --------
__device__ inline float wred64(float v) {
#pragma unroll
  for (int off = 1; off < 64; off <<= 1) v += __shfl_xor(v, off);
  return v;
}

__global__ __launch_bounds__(1024) void k2i_partial(const float* __restrict__ kv,
                                                    const float* __restrict__ qW,
                                                    const float* __restrict__ kW,
                                                    float* __restrict__ pars) {
  __shared__ alignas(16) float kl[4096];  // full 64x64 k_i map (16 KB), no halo
  __shared__ float wredl[16][18];         // per-wave: D[8], M[8], Q2[16]
  int bid = blockIdx.x;  // 192 = bc(64) * 3 + i
  int bc = bid / 3, i = bid - bc * 3;
  int b = bc >> 5, c = bc & 31;
  int tid = threadIdx.x;
  int lane = tid & 63, w = tid >> 6;  // w 0..15
  int xx = tid & 63;
  int ybase = tid >> 6;  // thread's rows are r*16 + ybase

  float qreg[4];
#pragma unroll
  for (int r = 0; r < 4; r++) {
    int px = r * 1024 + tid;  // row = r*16 + ybase, col = xx
    float q = 0.f, kk = 0.f;
    for (int ci = 0; ci < CC; ci++) {
      float val = kv[(b * CC + ci) * 4096 + px];
      q += qW[c * CC + ci] * val;
      kk += kW[(i * CC + c) * CC + ci] * val;
    }
    qreg[r] = q;
    kl[px] = kk;
  }
  __syncthreads();

  float q2 = 0.f;
#pragma unroll
  for (int r = 0; r < 4; r++) q2 += qreg[r] * qreg[r];
  q2 = wred64(q2);
  if (lane == 0) wredl[w][16] = q2;

  constexpr int DYt[8] = {-1, -1, -1, 0, 1, 1, 1, 0};
  constexpr int DXt[8] = {-1, 0, 1, 1, 1, 0, -1, -1};
  const int d = 1 << i;
#pragma unroll
  for (int n = 0; n < 8; n++) {
    const int dy = DYt[n], dx = DXt[n];
    int xn = xx + dx * d;
    bool xok = (xn >= 0 && xn < KVW);
    float dacc = 0.f, macc = 0.f;
#pragma unroll
    for (int r = 0; r < 4; r++) {
      int yy = r * 16 + ybase;
      int px = yy * KVW + xx;
      float kc = kl[px];
      int yn = yy + dy * d;
      float kn = (xok && yn >= 0 && yn < KVW) ? kl[yn * KVW + xn] : 0.f;
      float df = kc - kn;
      dacc += qreg[r] * df;
      macc += df * df;
    }
    dacc = wred64(dacc);
    macc = wred64(macc);
    if (lane == 0) {
      wredl[w][n] = dacc;
      wredl[w][8 + n] = macc;
    }
  }
  __syncthreads();

  float* pp = pars + (size_t)bid * 32;
  if (tid < 8) {
    float D = 0.f, M = 0.f;
    for (int w2 = 0; w2 < 16; w2++) {
      D += wredl[w2][tid];
      M += wredl[w2][8 + tid];
    }
    pp[tid] = D;
    pp[8 + tid] = M;
  }
  if (tid == 0) {
    float Q = 0.f;
    for (int w2 = 0; w2 < 16; w2++) Q += wredl[w2][16];
    pp[16] = Q;
  }
}

// ---------------- K2f: finalize scores [2,32,24] (verbatim) ----------
__global__ __launch_bounds__(64) void k2f_finalize(const float* __restrict__ pars,
                                                   float* __restrict__ scores) {
  __shared__ float srl[24];
  int bc = blockIdx.x;  // 64 = b*32 + c
  int t = threadIdx.x;
  if (t < 24) {
    int i = t >> 3, n = t & 7;
    const float* pp = pars + (size_t)(bc * 3 + i) * 32;
    float D = pp[n];
    float M = pp[8 + n];
    float Q = pars[(size_t)(bc * 3) * 32 + 16];  // Q2 identical across i; use i=0's
    float sr = D / (fmaxf(sqrtf(M), 1e-12f) * fmaxf(sqrtf(Q), 1e-12f));
    srl[t] = sr;
  }
  __syncthreads();
  if (t < 24) {
    float r2 = 0.f;
    for (int j = 0; j < 24; j++) r2 += srl[j] * srl[j];
    scores[bc * 24 + t] = srl[t] / fmaxf(sqrtf(r2), 1e-12f);
  }
}

// ---------------- K3a: v[i][b][c][px], bf16, 2 px/thread (verbatim) ----------
__global__ __launch_bounds__(256) void k3a_values(const float* __restrict__ cen,
                                                  const float* __restrict__ vW,
                                                  __hip_bfloat16* __restrict__ v) {
  int bid = blockIdx.x;  // 1024 = b(2) x blk(512)
  int b = bid >> 9, blk = bid & 511;
  int tid = threadIdx.x;
  int lane = tid & 63;
  int cg = __builtin_amdgcn_readfirstlane(tid >> 6);  // wave-uniform c group (8 c)
  int px = blk * 128 + lane * 2;

  float2 cr[CC];
#pragma unroll
  for (int ci = 0; ci < CC; ci++)
    cr[ci] = *(const float2*)(cen + (size_t)(b * CC + ci) * 65536 + px);

#pragma unroll
  for (int i = 0; i < 3; i++) {
#pragma unroll
    for (int cc = 0; cc < 8; cc++) {
      int c = cg * 8 + cc;
      const float* wp = vW + (i * CC + c) * CC;  // uniform -> s_load
      float a0 = 0.f, a1 = 0.f;
#pragma unroll
      for (int ci = 0; ci < CC; ci++) {
        a0 += wp[ci] * cr[ci].x;
        a1 += wp[ci] * cr[ci].y;
      }
      __hip_bfloat16 h0 = __float2bfloat16(a0);
      __hip_bfloat16 h1 = __float2bfloat16(a1);
      unsigned int pk = (unsigned int)(*(unsigned short*)&h0) |
                        ((unsigned int)(*(unsigned short*)&h1) << 16);
      *(unsigned int*)((unsigned short*)v + (((size_t)((i * 2 + b) * CC + c)) << 16) +
                       px) = pk;
    }
  }
}

// ---------------- K3b: combine taps + out conv + BN + ReLU (verbatim) --------
__global__ __launch_bounds__(256) void k3b_combine(const __hip_bfloat16* __restrict__ v,
                                                   const float* __restrict__ scores,
                                                   const float* __restrict__ oW,
                                                   const float* __restrict__ gamma,
                                                   const float* __restrict__ beta,
                                                   const float* __restrict__ mean,
                                                   const float* __restrict__ var,
                                                   float* __restrict__ out) {
  __shared__ alignas(16) float vt[3 * 24 * 24 * 4];  // [i][r][col][cp] halo-4 tiles
  __shared__ alignas(16) float sl[27][32];           // 0..23: s[j][c]; 24..26: S_i[c]
  __shared__ alignas(16) float owl[32][32];          // [co][c]
  __shared__ float bns[32], bnb[32];

  int bid = blockIdx.x;
  int b = bid >> 8, tile = bid & 255;
  int ty = tile >> 4, tx = tile & 15;
  int tid = threadIdx.x;
  int ly = tid >> 4, lx = tid & 15;

  for (int f = tid; f < 24 * 32; f += 256) {
    int j = f >> 5, c = f & 31;
    sl[j][c] = scores[(b * CC + c) * 24 + j];
  }
  for (int f = tid; f < 1024; f += 256) owl[f >> 5][f & 31] = oW[f];
  if (tid < 32) {
    float inv = rsqrtf(var[tid] + 1e-5f);
    float sc = gamma[tid] * inv;
    bns[tid] = sc;
    bnb[tid] = beta[tid] - mean[tid] * sc;
  }
  __syncthreads();
  if (tid < 32) {
#pragma unroll
    for (int i = 0; i < 3; i++) {
      float s = 0.f;
      for (int n = 0; n < 8; n++) s += sl[i * 8 + n][tid];
      sl[24 + i][tid] = s;
    }
  }

  int ldsoff[4], pxoff[4], ibase[4];
  bool okp[4];
#pragma unroll
  for (int it = 0; it < 4; it++) {
    int p = tid + it * 256;
    bool act = (p < 864);
    int pp = act ? p : 0;
    int i = pp / 288;
    int rem = pp - i * 288;
    int r = rem / 12;
    int col = (rem - r * 12) * 2;
    int gy = ty * 16 + r - 4, gx = tx * 16 + col - 4;
    okp[it] = act && gy >= 0 && gy < HW && gx >= 0 && gx < HW;
    pxoff[it] = gy * HW + gx;
    ibase[it] = (i * 2 + b) * CC;
    ldsoff[it] = ((i * 24 + r) * 24 + col) * 4;
  }

  constexpr int DYt[8] = {-1, -1, -1, 0, 1, 1, 1, 0};
  constexpr int DXt[8] = {-1, 0, 1, 1, 1, 0, -1, -1};

  float acc[32];
#pragma unroll
  for (int co = 0; co < 32; co++) acc[co] = 0.f;

  unsigned int pf[4][4];
  const unsigned short* vs = (const unsigned short*)v;

#pragma unroll
  for (int it = 0; it < 4; it++)
#pragma unroll
    for (int cp = 0; cp < 4; cp++)
      pf[it][cp] = okp[it]
                       ? *(const unsigned int*)(vs + (((size_t)(ibase[it] + cp)) << 16) +
                                                pxoff[it])
                       : 0u;

  for (int cg = 0; cg < 8; cg++) {
    __syncthreads();
#pragma unroll
    for (int it = 0; it < 4; it++) {
      if (it == 3 && tid >= 96) continue;  // p >= 864
      float4 lo, hi;
      lo.x = __uint_as_float(pf[it][0] << 16);
      lo.y = __uint_as_float(pf[it][1] << 16);
      lo.z = __uint_as_float(pf[it][2] << 16);
      lo.w = __uint_as_float(pf[it][3] << 16);
      hi.x = __uint_as_float(pf[it][0] & 0xffff0000u);
      hi.y = __uint_as_float(pf[it][1] & 0xffff0000u);
      hi.z = __uint_as_float(pf[it][2] & 0xffff0000u);
      hi.w = __uint_as_float(pf[it][3] & 0xffff0000u);
      *(float4*)&vt[ldsoff[it]] = lo;
      *(float4*)&vt[ldsoff[it] + 4] = hi;
    }
    if (cg < 7) {
      int cb = (cg + 1) * 4;
#pragma unroll
      for (int it = 0; it < 4; it++)
#pragma unroll
        for (int cp = 0; cp < 4; cp++)
          pf[it][cp] = okp[it] ? *(const unsigned int*)(vs +
                                                        (((size_t)(ibase[it] + cb + cp))
                                                         << 16) +
                                                        pxoff[it])
                               : 0u;
    }
    __syncthreads();

    float4 pre = {0.f, 0.f, 0.f, 0.f};
#pragma unroll
    for (int i = 0; i < 3; i++) {
      const int d = 1 << i;
      float4 S4 = *(const float4*)&sl[24 + i][cg * 4];
      float4 ctr = *(const float4*)&vt[((i * 24 + (ly + 4)) * 24 + (lx + 4)) * 4];
      pre.x += S4.x * ctr.x;
      pre.y += S4.y * ctr.y;
      pre.z += S4.z * ctr.z;
      pre.w += S4.w * ctr.w;
#pragma unroll
      for (int n = 0; n < 8; n++) {
        float4 sj = *(const float4*)&sl[i * 8 + n][cg * 4];
        float4 nb = *(const float4*)&vt[((i * 24 + (ly + 4 + DYt[n] * d)) * 24 +
                                         (lx + 4 + DXt[n] * d)) * 4];
        pre.x -= sj.x * nb.x;
        pre.y -= sj.y * nb.y;
        pre.z -= sj.z * nb.z;
        pre.w -= sj.w * nb.w;
      }
    }
#pragma unroll
    for (int co = 0; co < 32; co++) {
      float4 ow = *(const float4*)&owl[co][cg * 4];
      acc[co] += ow.x * pre.x + ow.y * pre.y + ow.z * pre.z + ow.w * pre.w;
    }
  }

  int gy = ty * 16 + ly, gx = tx * 16 + lx;
#pragma unroll
  for (int co = 0; co < 32; co++) {
    float val = acc[co] * bns[co] + bnb[co];
    out[((size_t)(b * CC + co) << 16) + gy * HW + gx] = fmaxf(val, 0.f);
  }
}

extern "C" void kernel_launch(void* const* d_in, const int* in_sizes, int n_in,
                              void* d_out, int out_size, void* d_ws, size_t ws_size,
                              hipStream_t stream) {
  const float* cen = (const float*)d_in[0];
  const float* trans_W = (const float*)d_in[1];
  const float* trans_b = (const float*)d_in[2];
  const float* query_W = (const float*)d_in[3];
  const float* value_W = (const float*)d_in[4];
  const float* key_W = (const float*)d_in[5];
  const float* out_W = (const float*)d_in[6];
  const float* bn_gamma = (const float*)d_in[7];
  const float* bn_beta = (const float*)d_in[8];
  const float* bn_mean = (const float*)d_in[9];
  const float* bn_var = (const float*)d_in[10];
  float* out = (float*)d_out;

  // workspace layout — unchanged:
  //   kv     [0,        524288)
  //   scores [524288,   530432)
  //   v      [532480,   25698304)  (bf16)
  //   pars   [25673728, 25698304)  -- aliases v tail; consumed by k2f before k3a.
  float* kv = (float*)d_ws;
  float* scores = (float*)((char*)d_ws + 524288);
  __hip_bfloat16* v = (__hip_bfloat16*)((char*)d_ws + 532480);
  float* pars = (float*)((char*)d_ws + 25673728);

  k1_trans<<<1024, 256, 0, stream>>>(cen, trans_W, trans_b, kv);
  k2i_partial<<<192, 1024, 0, stream>>>(kv, query_W, key_W, pars);
  k2f_finalize<<<64, 64, 0, stream>>>(pars, scores);
  k3a_values<<<1024, 256, 0, stream>>>(cen, value_W, v);  // clobbers pars (ok)
  k3b_combine<<<512, 256, 0, stream>>>(v, scores, out_W, bn_gamma, bn_beta, bn_mean,
                                       bn_var, out);
}

// Round 7
// 164.831 us; speedup vs baseline: 1.1289x; 1.0293x over previous
//
#include <hip/hip_runtime.h>
#include <hip/hip_bf16.h>

// ExpansionContrastModule on MI355X.
// b=2, C=32, H=W=256, kv grid 64x64, shifts (1,2,4), 8 diff kernels.
// ROUND 7 (= round-6 resubmit; round 6 was a GPU-acquisition timeout, never ran).
// Race fix: kv is [2,32,64,64] fp32 = 1 MB — in prior rounds it silently
// overlapped ws bytes [524288,1048576) (scores + v head); the 5-launch pipeline
// survived via ordering, but the k23_fat merge made K3a's v-writes race K2i's
// kv-reads (rounds 3/5 failures). Fix: kv now lives in d_out's first 1 MB
// (16 MB buffer, memset before launch, fully overwritten by k3b at the end).
// ws: srraw [0,6144), v [532480,25698304) — kv/srraw/v all disjoint -> no races.
// 3 launches: k1 -> k23_fat (K2i blocks 0..191 | K3a blocks 192..447) -> k3b.
// All inner-loop arithmetic byte-identical to passing round-2 bodies.

#define CC 32
#define HW 256
#define KVW 64

// ---------------- K1: 5x5 stride-4 pad-2 conv + bias -> kv [2,32,64,64] ----------------
// grid 1024 = b(2) x cog(8) x y(64); 4 waves: wave w -> ci range [8w, 8w+8),
// computes all 4 co of this cog. Partials combined via LDS (4 KB).
__global__ __launch_bounds__(256, 2) void k1_trans(const float* __restrict__ cen,
                                                   const float* __restrict__ tW,
                                                   const float* __restrict__ tB,
                                                   float* __restrict__ kv) {
  __shared__ alignas(16) float part[4][4][64];  // [ci-quarter][co][x], 4 KB
  int bid = blockIdx.x;
  int b = bid >> 9, cog = (bid >> 6) & 7, y = bid & 63;
  int tid = threadIdx.x;
  int x = tid & 63;
  int w = __builtin_amdgcn_readfirstlane(tid >> 6);  // wave id 0..3 = ci quarter
  int ci0 = w * 8;                                   // this wave's ci range [ci0, ci0+8)
  int co0 = cog * 4;                                 // block's 4 output channels

  float acc[4] = {0.f, 0.f, 0.f, 0.f};
  const float4 z4 = {0.f, 0.f, 0.f, 0.f};

  // Output row y taps input rows 4y-2+r, r=0..4. Max row 254 (in bounds);
  // only y==0 has rows -2,-1 -> clamp+skip (block-uniform).
  int roff[5];
  bool rok[5];
#pragma unroll
  for (int r = 0; r < 5; r++) {
    int row = 4 * y - 2 + r;
    rok[r] = (row >= 0);
    roff[r] = (row < 0 ? 0 : row) * HW;
  }

  for (int cc4 = 0; cc4 < 8; cc4 += 4) {
    int ci = ci0 + cc4;
    const float* pc[4];
#pragma unroll
    for (int c = 0; c < 4; c++) pc[c] = cen + (size_t)(b * CC + ci + c) * 65536 + 4 * x;
    float4 A[4][5], B[4][5];
#pragma unroll
    for (int c = 0; c < 4; c++) {
#pragma unroll
      for (int r = 0; r < 5; r++) {
        A[c][r] = (x > 0) ? *(const float4*)(pc[c] + roff[r] - 4) : z4;  // 4x-4..4x-1
        B[c][r] = *(const float4*)(pc[c] + roff[r]);                     // 4x..4x+3
      }
    }
#pragma unroll
    for (int r = 0; r < 5; r++) {
      if (!rok[r]) continue;  // block-uniform (only y==0, r<2)
#pragma unroll
      for (int c = 0; c < 4; c++) {
#pragma unroll
        for (int co = 0; co < 4; co++) {
          const float* wa = tW + ((co0 + co) * CC + ci + c) * 25 + r * 5;  // s_load
          acc[co] += wa[0] * A[c][r].z + wa[1] * A[c][r].w + wa[2] * B[c][r].x +
                     wa[3] * B[c][r].y + wa[4] * B[c][r].z;
        }
      }
    }
  }

#pragma unroll
  for (int co = 0; co < 4; co++) part[w][co][x] = acc[co];
  __syncthreads();

  // 256 outputs (4 co x 64 x), 256 threads -> 1 each.
  {
    int co = tid >> 6, xx = tid & 63;
    float s = part[0][co][xx] + part[1][co][xx] + part[2][co][xx] + part[3][co][xx];
    kv[((b * CC + co0 + co) * KVW + y) * KVW + xx] = s + tB[co0 + co];
  }
}

// ---------------- K23 fat: blocks 0..191 = K2i body; 192..447 = K3a body -------------
__device__ inline float wred64(float v) {
#pragma unroll
  for (int off = 1; off < 64; off <<= 1) v += __shfl_xor(v, off);
  return v;
}

__global__ __launch_bounds__(1024) void k23_fat(const float* __restrict__ kv,
                                                const float* __restrict__ qW,
                                                const float* __restrict__ kW,
                                                float* __restrict__ srraw,
                                                const float* __restrict__ cen,
                                                const float* __restrict__ vW,
                                                __hip_bfloat16* __restrict__ v) {
  __shared__ alignas(16) float kl[4096];  // k2i: full 64x64 k_i map (16 KB)
  __shared__ float wredl[16][18];         // k2i: per-wave D[8], M[8], Q2[16]
  int bid = blockIdx.x;
  int tid = threadIdx.x;

  if (bid < 192) {
    // ---- K2i body (verbatim round-2) + in-block score finalize ----
    int bc = bid / 3, i = bid - bc * 3;
    int b = bc >> 5, c = bc & 31;
    int lane = tid & 63, w = tid >> 6;  // w 0..15
    int xx = tid & 63;
    int ybase = tid >> 6;  // thread's rows are r*16 + ybase

    float qreg[4];
#pragma unroll
    for (int r = 0; r < 4; r++) {
      int px = r * 1024 + tid;  // row = r*16 + ybase, col = xx
      float q = 0.f, kk = 0.f;
      for (int ci = 0; ci < CC; ci++) {
        float val = kv[(b * CC + ci) * 4096 + px];
        q += qW[c * CC + ci] * val;
        kk += kW[(i * CC + c) * CC + ci] * val;
      }
      qreg[r] = q;
      kl[px] = kk;
    }
    __syncthreads();

    float q2 = 0.f;
#pragma unroll
    for (int r = 0; r < 4; r++) q2 += qreg[r] * qreg[r];
    q2 = wred64(q2);
    if (lane == 0) wredl[w][16] = q2;

    constexpr int DYt[8] = {-1, -1, -1, 0, 1, 1, 1, 0};
    constexpr int DXt[8] = {-1, 0, 1, 1, 1, 0, -1, -1};
    const int d = 1 << i;
#pragma unroll
    for (int n = 0; n < 8; n++) {
      const int dy = DYt[n], dx = DXt[n];
      int xn = xx + dx * d;
      bool xok = (xn >= 0 && xn < KVW);
      float dacc = 0.f, macc = 0.f;
#pragma unroll
      for (int r = 0; r < 4; r++) {
        int yy = r * 16 + ybase;
        int px = yy * KVW + xx;
        float kc = kl[px];
        int yn = yy + dy * d;
        float kn = (xok && yn >= 0 && yn < KVW) ? kl[yn * KVW + xn] : 0.f;
        float df = kc - kn;
        dacc += qreg[r] * df;
        macc += df * df;
      }
      dacc = wred64(dacc);
      macc = wred64(macc);
      if (lane == 0) {
        wredl[w][n] = dacc;
        wredl[w][8 + n] = macc;
      }
    }
    __syncthreads();

    // Finalize this block's 8 raw cosine sims (D, M, Q all local; Q bitwise
    // identical across i since qreg and the summation order don't depend on i).
    if (tid < 8) {
      float D = 0.f, M = 0.f, Q = 0.f;
      for (int w2 = 0; w2 < 16; w2++) {
        D += wredl[w2][tid];
        M += wredl[w2][8 + tid];
        Q += wredl[w2][16];
      }
      float sr = D / (fmaxf(sqrtf(M), 1e-12f) * fmaxf(sqrtf(Q), 1e-12f));
      srraw[bc * 24 + i * 8 + tid] = sr;
    }
  } else {
    // ---- K3a body (round-2 arithmetic, reshaped: 4 virtual 256-thread sub-blocks) ----
    int bid2 = bid - 192;            // 0..255
    int vb = bid2 * 4 + (tid >> 8);  // virtual block 0..1023
    int b = vb >> 9, blk = vb & 511;
    int lane = tid & 63;
    int cg = __builtin_amdgcn_readfirstlane((tid >> 6) & 3);  // wave-uniform c group
    int px = blk * 128 + lane * 2;

    float2 cr[CC];
#pragma unroll
    for (int ci = 0; ci < CC; ci++)
      cr[ci] = *(const float2*)(cen + (size_t)(b * CC + ci) * 65536 + px);

#pragma unroll
    for (int i = 0; i < 3; i++) {
#pragma unroll
      for (int cc = 0; cc < 8; cc++) {
        int c = cg * 8 + cc;
        const float* wp = vW + (i * CC + c) * CC;  // uniform -> s_load
        float a0 = 0.f, a1 = 0.f;
#pragma unroll
        for (int ci = 0; ci < CC; ci++) {
          a0 += wp[ci] * cr[ci].x;
          a1 += wp[ci] * cr[ci].y;
        }
        __hip_bfloat16 h0 = __float2bfloat16(a0);
        __hip_bfloat16 h1 = __float2bfloat16(a1);
        unsigned int pk = (unsigned int)(*(unsigned short*)&h0) |
                          ((unsigned int)(*(unsigned short*)&h1) << 16);
        *(unsigned int*)((unsigned short*)v + (((size_t)((i * 2 + b) * CC + c)) << 16) +
                         px) = pk;
      }
    }
  }
}

// ---------------- K3b: score l2norm (folded K2f) + combine + out conv + BN + ReLU -----
__global__ __launch_bounds__(256) void k3b_combine(const __hip_bfloat16* __restrict__ v,
                                                   const float* __restrict__ srraw,
                                                   const float* __restrict__ oW,
                                                   const float* __restrict__ gamma,
                                                   const float* __restrict__ beta,
                                                   const float* __restrict__ mean,
                                                   const float* __restrict__ var,
                                                   float* __restrict__ out) {
  __shared__ alignas(16) float vt[3 * 24 * 24 * 4];  // [i][r][col][cp] halo-4 tiles
  __shared__ alignas(16) float sl[27][32];           // 0..23: s[j][c]; 24..26: S_i[c]
  __shared__ alignas(16) float owl[32][32];          // [co][c]
  __shared__ float bns[32], bnb[32];

  int bid = blockIdx.x;
  int b = bid >> 8, tile = bid & 255;
  int ty = tile >> 4, tx = tile & 15;
  int tid = threadIdx.x;
  int ly = tid >> 4, lx = tid & 15;

  // Raw cosine sims [24 j][32 c] for this b.
  for (int f = tid; f < 768; f += 256) {
    int j = f >> 5, c = f & 31;
    sl[j][c] = srraw[(b * CC + c) * 24 + j];
  }
  for (int f = tid; f < 1024; f += 256) owl[f >> 5][f & 31] = oW[f];
  if (tid < 32) {
    float inv = rsqrtf(var[tid] + 1e-5f);
    float sc = gamma[tid] * inv;
    bns[tid] = sc;
    bnb[tid] = beta[tid] - mean[tid] * sc;
  }
  __syncthreads();
  if (tid < 32) {
    // l2norm across the 24 scores, then per-shift sums (protected by the
    // __syncthreads() at the head of the main loop before any sl reads).
    float r2 = 0.f;
#pragma unroll
    for (int j = 0; j < 24; j++) {
      float s = sl[j][tid];
      r2 += s * s;
    }
    float dn = fmaxf(sqrtf(r2), 1e-12f);
#pragma unroll
    for (int j = 0; j < 24; j++) sl[j][tid] /= dn;
#pragma unroll
    for (int i = 0; i < 3; i++) {
      float s = 0.f;
      for (int n = 0; n < 8; n++) s += sl[i * 8 + n][tid];
      sl[24 + i][tid] = s;
    }
  }

  int ldsoff[4], pxoff[4], ibase[4];
  bool okp[4];
#pragma unroll
  for (int it = 0; it < 4; it++) {
    int p = tid + it * 256;
    bool act = (p < 864);
    int pp = act ? p : 0;
    int i = pp / 288;
    int rem = pp - i * 288;
    int r = rem / 12;
    int col = (rem - r * 12) * 2;
    int gy = ty * 16 + r - 4, gx = tx * 16 + col - 4;
    okp[it] = act && gy >= 0 && gy < HW && gx >= 0 && gx < HW;
    pxoff[it] = gy * HW + gx;
    ibase[it] = (i * 2 + b) * CC;
    ldsoff[it] = ((i * 24 + r) * 24 + col) * 4;
  }

  constexpr int DYt[8] = {-1, -1, -1, 0, 1, 1, 1, 0};
  constexpr int DXt[8] = {-1, 0, 1, 1, 1, 0, -1, -1};

  float acc[32];
#pragma unroll
  for (int co = 0; co < 32; co++) acc[co] = 0.f;

  unsigned int pf[4][4];
  const unsigned short* vs = (const unsigned short*)v;

#pragma unroll
  for (int it = 0; it < 4; it++)
#pragma unroll
    for (int cp = 0; cp < 4; cp++)
      pf[it][cp] = okp[it]
                       ? *(const unsigned int*)(vs + (((size_t)(ibase[it] + cp)) << 16) +
                                                pxoff[it])
                       : 0u;

  for (int cg = 0; cg < 8; cg++) {
    __syncthreads();
#pragma unroll
    for (int it = 0; it < 4; it++) {
      if (it == 3 && tid >= 96) continue;  // p >= 864
      float4 lo, hi;
      lo.x = __uint_as_float(pf[it][0] << 16);
      lo.y = __uint_as_float(pf[it][1] << 16);
      lo.z = __uint_as_float(pf[it][2] << 16);
      lo.w = __uint_as_float(pf[it][3] << 16);
      hi.x = __uint_as_float(pf[it][0] & 0xffff0000u);
      hi.y = __uint_as_float(pf[it][1] & 0xffff0000u);
      hi.z = __uint_as_float(pf[it][2] & 0xffff0000u);
      hi.w = __uint_as_float(pf[it][3] & 0xffff0000u);
      *(float4*)&vt[ldsoff[it]] = lo;
      *(float4*)&vt[ldsoff[it] + 4] = hi;
    }
    if (cg < 7) {
      int cb = (cg + 1) * 4;
#pragma unroll
      for (int it = 0; it < 4; it++)
#pragma unroll
        for (int cp = 0; cp < 4; cp++)
          pf[it][cp] = okp[it] ? *(const unsigned int*)(vs +
                                                        (((size_t)(ibase[it] + cb + cp))
                                                         << 16) +
                                                        pxoff[it])
                               : 0u;
    }
    __syncthreads();

    float4 pre = {0.f, 0.f, 0.f, 0.f};
#pragma unroll
    for (int i = 0; i < 3; i++) {
      const int d = 1 << i;
      float4 S4 = *(const float4*)&sl[24 + i][cg * 4];
      float4 ctr = *(const float4*)&vt[((i * 24 + (ly + 4)) * 24 + (lx + 4)) * 4];
      pre.x += S4.x * ctr.x;
      pre.y += S4.y * ctr.y;
      pre.z += S4.z * ctr.z;
      pre.w += S4.w * ctr.w;
#pragma unroll
      for (int n = 0; n < 8; n++) {
        float4 sj = *(const float4*)&sl[i * 8 + n][cg * 4];
        float4 nb = *(const float4*)&vt[((i * 24 + (ly + 4 + DYt[n] * d)) * 24 +
                                         (lx + 4 + DXt[n] * d)) * 4];
        pre.x -= sj.x * nb.x;
        pre.y -= sj.y * nb.y;
        pre.z -= sj.z * nb.z;
        pre.w -= sj.w * nb.w;
      }
    }
#pragma unroll
    for (int co = 0; co < 32; co++) {
      float4 ow = *(const float4*)&owl[co][cg * 4];
      acc[co] += ow.x * pre.x + ow.y * pre.y + ow.z * pre.z + ow.w * pre.w;
    }
  }

  int gy = ty * 16 + ly, gx = tx * 16 + lx;
#pragma unroll
  for (int co = 0; co < 32; co++) {
    float val = acc[co] * bns[co] + bnb[co];
    out[((size_t)(b * CC + co) << 16) + gy * HW + gx] = fmaxf(val, 0.f);
  }
}

extern "C" void kernel_launch(void* const* d_in, const int* in_sizes, int n_in,
                              void* d_out, int out_size, void* d_ws, size_t ws_size,
                              hipStream_t stream) {
  const float* cen = (const float*)d_in[0];
  const float* trans_W = (const float*)d_in[1];
  const float* trans_b = (const float*)d_in[2];
  const float* query_W = (const float*)d_in[3];
  const float* value_W = (const float*)d_in[4];
  const float* key_W = (const float*)d_in[5];
  const float* out_W = (const float*)d_in[6];
  const float* bn_gamma = (const float*)d_in[7];
  const float* bn_beta = (const float*)d_in[8];
  const float* bn_mean = (const float*)d_in[9];
  const float* bn_var = (const float*)d_in[10];
  float* out = (float*)d_out;

  // Buffer plan (race-free):
  //   kv    = d_out[0, 1048576)   -- 1 MB fp32 scratch inside the 16 MB output
  //                                   buffer; fully overwritten by k3b at the end.
  //   srraw = ws[0, 6144)          -- raw cosine sims [2,32,24]
  //   v     = ws[532480, 25698304) -- bf16 values (offset kept from proven layout)
  // Disjointness: kv (d_out) vs srraw/v (ws) are different allocations; srraw and
  // v don't overlap. Inside k23_fat, K2i reads kv + writes srraw while K3a
  // writes v -> no races. k3b reads srraw+v, writes every element of out.
  float* kv = (float*)d_out;
  float* srraw = (float*)d_ws;
  __hip_bfloat16* v = (__hip_bfloat16*)((char*)d_ws + 532480);

  k1_trans<<<1024, 256, 0, stream>>>(cen, trans_W, trans_b, kv);
  k23_fat<<<448, 1024, 0, stream>>>(kv, query_W, key_W, srraw, cen, value_W, v);
  k3b_combine<<<512, 256, 0, stream>>>(v, srraw, out_W, bn_gamma, bn_beta, bn_mean,
                                       bn_var, out);
}